// Round 15
// baseline (130.445 us; speedup 1.0000x reference)
//
#include <hip/hip_runtime.h>
#include <hip/hip_fp16.h>
#include <math.h>

#define CC 64
#define KK 16
#define NNODES 15
#define DD 512      // input feature dim
#define MM 512      // output dim
#define NN 16384    // rows

typedef _Float16 half8 __attribute__((ext_vector_type(8)));
typedef float f32x4 __attribute__((ext_vector_type(4)));
typedef unsigned long long u64;

// ---------------------------------------------------------------------------
// XLA/Eigen fast-tanh for f32 (bit-exact vs JAX's jnp.tanh lowering).
// ---------------------------------------------------------------------------
__device__ __forceinline__ float xla_tanhf(float x) {
    const float kMax = 7.90531110763549805f;
    bool tiny = fabsf(x) < 0.0004f;
    float xc = fminf(fmaxf(x, -kMax), kMax);
    float x2 = __fmul_rn(xc, xc);
    float p = __fmaf_rn(x2, -2.76076847742355e-16f, 2.00018790482477e-13f);
    p = __fmaf_rn(x2, p, -8.60467152213735e-11f);
    p = __fmaf_rn(x2, p, 5.12229709037114e-08f);
    p = __fmaf_rn(x2, p, 1.48572235717979e-05f);
    p = __fmaf_rn(x2, p, 6.37261928875436e-04f);
    p = __fmaf_rn(x2, p, 4.89352455891786e-03f);
    p = __fmul_rn(xc, p);
    float q = __fmaf_rn(x2, 1.19825839466702e-06f, 1.18534705686654e-04f);
    q = __fmaf_rn(x2, q, 2.26843463243900e-03f);
    q = __fmaf_rn(x2, q, 4.89352518554385e-03f);
    return tiny ? x : __fdiv_rn(p, q);
}

// ---------------------------------------------------------------------------
// Kernel 1: pack L (M, C, K) fp32 -> Bpk fp16 in MFMA-B fragment order.
// B operand of mfma_f32_16x16x32_f16: lane l holds B[k=(l>>4)*8+j][col=l&15],
// j = 0..7 packed in 4 VGPRs. Layout: Bpk[ks][mtile][lane] = uint4 (8 halves).
// (round-1 verified)
// ---------------------------------------------------------------------------
__global__ __launch_bounds__(256) void pack_bfrag(const float* __restrict__ L,
                                                  uint4* __restrict__ Bpk) {
    const int t    = blockIdx.x * 256 + threadIdx.x;  // 0..65535
    const int lane = t & 63;
    const int mtg  = (t >> 6) & 31;                   // global m-tile 0..31
    const int ks   = t >> 11;                         // k-step 0..31
    const int kbase = ks * 32 + ((lane >> 4) << 3);   // 8-aligned k window
    const int c     = kbase >> 4;                     // subspace
    const int slot0 = kbase & 15;                     // 0 or 8
    const int m     = (mtg << 4) + (lane & 15);

    const float* src = L + ((size_t)m * CC + c) * KK + slot0;
    float4 v0 = ((const float4*)src)[0];
    float4 v1 = ((const float4*)src)[1];
    union { half8 h; uint4 u; } pk;
    pk.h[0] = (_Float16)v0.x; pk.h[1] = (_Float16)v0.y;
    pk.h[2] = (_Float16)v0.z; pk.h[3] = (_Float16)v0.w;
    pk.h[4] = (_Float16)v1.x; pk.h[5] = (_Float16)v1.y;
    pk.h[6] = (_Float16)v1.z; pk.h[7] = (_Float16)v1.w;
    Bpk[t] = pk.u;
}

// ---------------------------------------------------------------------------
// Kernel 2: ENCODE (standalone, unchanged from round 5 — clean counters).
// ---------------------------------------------------------------------------
__global__ __launch_bounds__(256, 4) void encode_kernel(const float* __restrict__ I,
                                                        const float* __restrict__ A,
                                                        const float* __restrict__ T,
                                                        unsigned* __restrict__ codesG) {
    __shared__ float sA[32 * 64];              // TRANSPOSED: [s*4+d][c]
    __shared__ float sT[CC * NNODES];

    const int tid = threadIdx.x;
    for (int i = tid; i < CC * 32; i += 256) sA[(i & 31) * 64 + (i >> 5)] = A[i];
    for (int i = tid; i < CC * NNODES; i += 256) sT[i] = T[i];
    __syncthreads();

    const int lane = tid & 63;
    const int c    = lane;
    const int w    = ((blockIdx.x & 3) << 2) + (tid >> 6);   // 0..15
    const int tile = blockIdx.x >> 2;
    const int n0   = tile * 64;

    float a_[32];
#pragma unroll
    for (int i = 0; i < 32; ++i) a_[i] = sA[i * 64 + c];
    float tt[NNODES];
#pragma unroll
    for (int i = 0; i < NNODES; ++i) tt[i] = sT[c * NNODES + i];

    const int lvl[NNODES] = {0, 1, 1, 2, 2, 2, 2, 3, 3, 3, 3, 3, 3, 3, 3};
    unsigned codeWord = 0;
#pragma unroll 2
    for (int rr = 0; rr < 4; ++rr) {
        const int rl = (rr << 4) + w;
        const float* Ij = I + (size_t)(n0 + rl) * DD + c * 8;
        float4 v0 = ((const float4*)Ij)[0];
        float4 v1 = ((const float4*)Ij)[1];
        float iv[8] = {v0.x, v0.y, v0.z, v0.w, v1.x, v1.y, v1.z, v1.w};

        float t[4] = {0.f, 0.f, 0.f, 0.f};
#pragma unroll
        for (int s = 0; s < 8; ++s) {
            float v = iv[s];
#pragma unroll
            for (int d = 0; d < 4; ++d)
                t[d] = __fmaf_rn(v, a_[(s << 2) + d], t[d]);
        }

        float th[NNODES];
#pragma unroll
        for (int i = 0; i < NNODES; ++i) {
            float h = __fsub_rn(t[lvl[i]], tt[i]);
            th[i] = xla_tanhf(h);
        }

        int best = 0;
        float bestv = -3.0e38f;
#pragma unroll
        for (int k = 0; k < KK; ++k) {
            int node = 0;
            float s = 0.f;
#pragma unroll
            for (int l = 0; l < 4; ++l) {
                int bit = (k >> (3 - l)) & 1;
                s = __fadd_rn(s, bit ? th[node] : -th[node]);
                node = 2 * node + 1 + bit;
            }
            if (s > bestv) { bestv = s; best = k; }   // strict >: first-max
        }
        codeWord |= ((unsigned)best) << (rr << 3);
    }
    codesG[(size_t)tile * 1024 + (w << 6) + c] = codeWord;
}

// ---------------------------------------------------------------------------
// Kernel 3: DECODE v6 — register-staged, barrier-free, 8nt x 2mt (L2-BW fix).
// R13 post-mortem: ALL reg variants stuck at decode ~24-30us because they
// are L2-BANDWIDTH-bound, not scheduling-bound. Chip B-traffic = 16.8GB /
// (rows per wave): at 64 rows/wave (4nt) = 262MB, which at the 8.3us MFMA
// floor needs 31 TB/s ~ the 34.5 TB/s L2 ceiling -> impossible; effective
// ~11 TB/s -> ~24us. Depth-8 neutral (R12) and TLP worse (R13: 2x one-hot
// VALU, same traffic) both confirm.
// Fix: wave = 8nt x 2mt (128 rows x 32 cols) -> traffic 131MB (x0.5).
// Block = 128 rows x 128 cols, 4 waves = 4 col-strips SHARING rows (code
// words L1-shared). Grid 512, (256,2) = 2 waves/SIMD (R13: more waves
// hurts). Per wave/ks: 16 MFMA (310cy) + 8 builds (~260cy VALU, under the
// 620cy/SIMD MFMA demand) + 4 loads, depth-4 named sets (rule-#20 safe).
// VGPR ~130 (acc 64 + sets 40 + misc) < 256 cap. Tripwire: FETCH >> 3MB.
// ---------------------------------------------------------------------------
#define LOADSET(S, ks_)                              \
    b##S##0 = Bp[((ks_) * 32 + 0) * 64];             \
    b##S##1 = Bp[((ks_) * 32 + 1) * 64];             \
    cw##S = cG0[(ks_) << 1];                         \
    cx##S = cG1[(ks_) << 1];

#define ONEHOT(cwv, ntb, dst) do {                                        \
    unsigned ud  = (((cwv) >> ((ntb) << 3)) & 255u) - (unsigned)sb;       \
    unsigned ud2 = ud - 4u;                                               \
    u64 lo = (ud  < 4u) ? (0x3C00ull << ((ud  & 3u) << 4)) : 0ull;        \
    u64 hi = (ud2 < 4u) ? (0x3C00ull << ((ud2 & 3u) << 4)) : 0ull;        \
    union { u64 q[2]; half8 h; } uu; uu.q[0] = lo; uu.q[1] = hi;          \
    dst = uu.h;                                                           \
} while (0)

#define COMPUTESET(S) do {                                                \
    half8 a_[8];                                                          \
    ONEHOT(cw##S, 0, a_[0]); ONEHOT(cw##S, 1, a_[1]);                     \
    ONEHOT(cw##S, 2, a_[2]); ONEHOT(cw##S, 3, a_[3]);                     \
    ONEHOT(cx##S, 0, a_[4]); ONEHOT(cx##S, 1, a_[5]);                     \
    ONEHOT(cx##S, 2, a_[6]); ONEHOT(cx##S, 3, a_[7]);                     \
    union { uint4 u; half8 h; } q0, q1;                                   \
    q0.u = b##S##0; q1.u = b##S##1;                                       \
    _Pragma("unroll")                                                     \
    for (int nt = 0; nt < 8; ++nt) {                                      \
        acc[nt][0] = __builtin_amdgcn_mfma_f32_16x16x32_f16(a_[nt], q0.h, acc[nt][0], 0, 0, 0); \
        acc[nt][1] = __builtin_amdgcn_mfma_f32_16x16x32_f16(a_[nt], q1.h, acc[nt][1], 0, 0, 0); \
    }                                                                     \
} while (0)

__global__ __launch_bounds__(256, 2) void decode_kernel(const unsigned* __restrict__ codesG,
                                                        const uint4* __restrict__ Bpk,
                                                        float* __restrict__ out) {
    const int tid = threadIdx.x;
    const int bn  = blockIdx.x >> 2;        // 0..127 (128-row group)
    const int bm  = blockIdx.x & 3;         // 0..3   (128-col strip)
    const int n0  = bn << 7;
    const int m0  = bm << 7;

    const int w    = tid >> 6;              // wave 0..3 = 32-col substrip
    const int lane = tid & 63;
    const int r15  = lane & 15;
    const int sb   = ((lane >> 4) & 1) << 3;
    const int chi  = lane >> 5;

    // per-lane bases: B frag (ks,j) at Bp[(ks*32 + j)*64]
    const uint4* Bp = Bpk + ((bm << 3) + (w << 1)) * 64 + lane;
    // codes: two 64-row tiles; cw covers nt 0..3, cx covers nt 4..7
    const unsigned* cG0 = codesG + ((size_t)(bn << 1) << 10) + (r15 << 6) + chi;
    const unsigned* cG1 = cG0 + 1024;

    f32x4 acc[8][2];
#pragma unroll
    for (int nt = 0; nt < 8; ++nt) {
        acc[nt][0] = (f32x4){0.f, 0.f, 0.f, 0.f};
        acc[nt][1] = (f32x4){0.f, 0.f, 0.f, 0.f};
    }

    uint4 bA0, bA1; unsigned cwA, cxA;
    uint4 bB0, bB1; unsigned cwB, cxB;
    uint4 bC0, bC1; unsigned cwC, cxC;
    uint4 bD0, bD1; unsigned cwD, cxD;

    // prologue: 4 k-steps in flight (16 outstanding loads)
    LOADSET(A, 0)
    LOADSET(B, 1)
    LOADSET(C, 2)
    LOADSET(D, 3)

#pragma unroll 1
    for (int g = 0; g < 8; ++g) {
        const int ks = g << 2;
        const bool more = g < 7;
        COMPUTESET(A); if (more) { LOADSET(A, ks + 4) }
        COMPUTESET(B); if (more) { LOADSET(B, ks + 5) }
        COMPUTESET(C); if (more) { LOADSET(C, ks + 6) }
        COMPUTESET(D); if (more) { LOADSET(D, ks + 7) }
    }

    // ---- epilogue: D layout col=lane&15, row=(lane>>4)*4+reg ----
    const int rbase = (lane >> 4) << 2;
#pragma unroll
    for (int nt = 0; nt < 8; ++nt) {
#pragma unroll
        for (int r = 0; r < 4; ++r) {
            float* o = out + (size_t)(n0 + (nt << 4) + rbase + r) * MM
                           + m0 + (w << 5) + r15;
            o[0]  = acc[nt][0][r];
            o[16] = acc[nt][1][r];
        }
    }
}

// ---------------------------------------------------------------------------
extern "C" void kernel_launch(void* const* d_in, const int* in_sizes, int n_in,
                              void* d_out, int out_size, void* d_ws, size_t ws_size,
                              hipStream_t stream) {
    const float* I = (const float*)d_in[0];  // (N, D) fp32
    const float* A = (const float*)d_in[1];  // (C, 8, 4) fp32
    const float* T = (const float*)d_in[2];  // (C*15,) fp32
    const float* L = (const float*)d_in[3];  // (M, C, K) fp32
    // d_in[4] = S, d_in[5] = B: structural constants, hard-coded.

    uint4* Bpk = (uint4*)d_ws;                               // 1 MB fp16 LUT frags
    unsigned* codesG = (unsigned*)((char*)d_ws + (1 << 20)); // 1 MB packed codes
    float* out = (float*)d_out;                              // (N, M) fp32

    hipLaunchKernelGGL(pack_bfrag, dim3(256), dim3(256), 0, stream, L, Bpk);
    hipLaunchKernelGGL(encode_kernel, dim3(1024), dim3(256), 0, stream, I, A, T, codesG);
    hipLaunchKernelGGL(decode_kernel, dim3(512), dim3(256), 0, stream, codesG, Bpk, out);
}

// Round 17
// 126.969 us; speedup vs baseline: 1.0274x; 1.0274x over previous
//
#include <hip/hip_runtime.h>
#include <hip/hip_fp16.h>
#include <math.h>

#define CC 64
#define KK 16
#define NNODES 15
#define DD 512      // input feature dim
#define MM 512      // output dim
#define NN 16384    // rows

typedef _Float16 half8 __attribute__((ext_vector_type(8)));
typedef float f32x16 __attribute__((ext_vector_type(16)));
typedef unsigned long long u64;

// ---------------------------------------------------------------------------
// XLA/Eigen fast-tanh for f32 (bit-exact vs JAX's jnp.tanh lowering).
// ---------------------------------------------------------------------------
__device__ __forceinline__ float xla_tanhf(float x) {
    const float kMax = 7.90531110763549805f;
    bool tiny = fabsf(x) < 0.0004f;
    float xc = fminf(fmaxf(x, -kMax), kMax);
    float x2 = __fmul_rn(xc, xc);
    float p = __fmaf_rn(x2, -2.76076847742355e-16f, 2.00018790482477e-13f);
    p = __fmaf_rn(x2, p, -8.60467152213735e-11f);
    p = __fmaf_rn(x2, p, 5.12229709037114e-08f);
    p = __fmaf_rn(x2, p, 1.48572235717979e-05f);
    p = __fmaf_rn(x2, p, 6.37261928875436e-04f);
    p = __fmaf_rn(x2, p, 4.89352455891786e-03f);
    p = __fmul_rn(xc, p);
    float q = __fmaf_rn(x2, 1.19825839466702e-06f, 1.18534705686654e-04f);
    q = __fmaf_rn(x2, q, 2.26843463243900e-03f);
    q = __fmaf_rn(x2, q, 4.89352518554385e-03f);
    return tiny ? x : __fdiv_rn(p, q);
}

// ---------------------------------------------------------------------------
// Kernel 1 (FUSED prep): blocks 0..255 pack L -> Bpk32 (32x32x16 B-fragment
// order); blocks 256..1279 run the round-5 bit-exact encode. Fusion removes
// one kernel launch + gap. Branch is blockIdx-uniform.
//
// Bpk32 layout for mfma_f32_32x32x16_f16 B operand: lane l holds
// B[k=(l>>5)*8+j][col=l&31], j=0..7 in 4 VGPRs (same lane pattern as the
// round-1-verified 16x16 layout, widened to 32 cols / 16 k).
// Bpk32[ks(0..63)][mt32(0..15)][lane] = uint4; ks IS the subspace index.
// ---------------------------------------------------------------------------
__global__ __launch_bounds__(256, 4) void prep_kernel(const float* __restrict__ I,
                                                      const float* __restrict__ A,
                                                      const float* __restrict__ T,
                                                      const float* __restrict__ L,
                                                      uint4* __restrict__ Bpk,
                                                      unsigned* __restrict__ codesG) {
    __shared__ float sA[32 * 64];              // TRANSPOSED: [s*4+d][c]
    __shared__ float sT[CC * NNODES];

    const int tid = threadIdx.x;

    if (blockIdx.x < 256) {
        // ---------------- pack32 ----------------
        const int t    = blockIdx.x * 256 + tid;   // 0..65535
        const int lane = t & 63;
        const int mtg  = (t >> 6) & 15;            // 32-col tile 0..15
        const int ks   = t >> 10;                  // subspace 0..63
        const int col  = (mtg << 5) + (lane & 31);
        const int slot0 = (lane >> 5) << 3;        // 0 or 8

        const float* src = L + ((size_t)col * CC + ks) * KK + slot0;
        float4 v0 = ((const float4*)src)[0];
        float4 v1 = ((const float4*)src)[1];
        union { half8 h; uint4 u; } pk;
        pk.h[0] = (_Float16)v0.x; pk.h[1] = (_Float16)v0.y;
        pk.h[2] = (_Float16)v0.z; pk.h[3] = (_Float16)v0.w;
        pk.h[4] = (_Float16)v1.x; pk.h[5] = (_Float16)v1.y;
        pk.h[6] = (_Float16)v1.z; pk.h[7] = (_Float16)v1.w;
        Bpk[t] = pk.u;
        return;
    }

    // ---------------- encode (round-5 bit-exact; unchanged math) ----------------
    const int bid = blockIdx.x - 256;              // 0..1023
    for (int i = tid; i < CC * 32; i += 256) sA[(i & 31) * 64 + (i >> 5)] = A[i];
    for (int i = tid; i < CC * NNODES; i += 256) sT[i] = T[i];
    __syncthreads();

    const int lane = tid & 63;
    const int c    = lane;
    const int w    = ((bid & 3) << 2) + (tid >> 6);   // 0..15
    const int tile = bid >> 2;
    const int n0   = tile * 64;

    float a_[32];
#pragma unroll
    for (int i = 0; i < 32; ++i) a_[i] = sA[i * 64 + c];
    float tt[NNODES];
#pragma unroll
    for (int i = 0; i < NNODES; ++i) tt[i] = sT[c * NNODES + i];

    const int lvl[NNODES] = {0, 1, 1, 2, 2, 2, 2, 3, 3, 3, 3, 3, 3, 3, 3};
    unsigned codeWord = 0;
#pragma unroll 2
    for (int rr = 0; rr < 4; ++rr) {
        const int rl = (rr << 4) + w;
        const float* Ij = I + (size_t)(n0 + rl) * DD + c * 8;
        float4 v0 = ((const float4*)Ij)[0];
        float4 v1 = ((const float4*)Ij)[1];
        float iv[8] = {v0.x, v0.y, v0.z, v0.w, v1.x, v1.y, v1.z, v1.w};

        float t[4] = {0.f, 0.f, 0.f, 0.f};
#pragma unroll
        for (int s = 0; s < 8; ++s) {
            float v = iv[s];
#pragma unroll
            for (int d = 0; d < 4; ++d)
                t[d] = __fmaf_rn(v, a_[(s << 2) + d], t[d]);
        }

        float th[NNODES];
#pragma unroll
        for (int i = 0; i < NNODES; ++i) {
            float h = __fsub_rn(t[lvl[i]], tt[i]);
            th[i] = xla_tanhf(h);
        }

        int best = 0;
        float bestv = -3.0e38f;
#pragma unroll
        for (int k = 0; k < KK; ++k) {
            int node = 0;
            float s = 0.f;
#pragma unroll
            for (int l = 0; l < 4; ++l) {
                int bit = (k >> (3 - l)) & 1;
                s = __fadd_rn(s, bit ? th[node] : -th[node]);
                node = 2 * node + 1 + bit;
            }
            if (s > bestv) { bestv = s; best = k; }   // strict >: first-max
        }
        codeWord |= ((unsigned)best) << (rr << 3);
    }
    // word [tile][r15=w][c]: byte rr = code of row rr*16+w
    codesG[(size_t)tile * 1024 + (w << 6) + c] = codeWord;
}

// ---------------------------------------------------------------------------
// Kernel 2: DECODE v7 — R11 structure (best: 123.3us) + 32x32x16 MFMA.
// R15 post-mortem: latency-depth (R12), TLP (R13), and L2-traffic (R15)
// theories ALL falsified; R11 remains best. Untested lever with uarch
// backing: 32x32 MFMA runs at 2495 TF vs 16x16's 2075 (m119/m06, +17%
// less pipe time for identical MACs; floor 8.3 -> 6.9us). K=16 = exactly
// one subspace/step; one code-word u32 serves both nt builds.
// Wave = 2nt x 2mt of 32x32 tiles = 64 rows x 64 cols (same as R11's
// coverage; acc 4x16 = 64 VGPR same; builds/wave/MACs identical; traffic
// 268MB same). Block = 128x128 (2wn x 2wm), grid 512, (256,2) barrier-free
// depth-4 named sets (rule-#20 safe). VGPR ~125.
// C/D layout (m74/m101-verified): col=lane&31, row=(reg&3)+8*(reg>>2)
// +4*(lane>>5). A/B lane pattern: row/col=l&31, slots=(l>>5)*8+j.
// Tripwires: absmax != 0.25 -> layout inference wrong -> revert to R11.
// ---------------------------------------------------------------------------
#define LOADSET(S, ks_)                              \
    b##S##0 = Bp[((ks_) * 16 + 0) * 64];             \
    b##S##1 = Bp[((ks_) * 16 + 1) * 64];             \
    cw##S = cG[(ks_)];

#define COMPUTESET(S) do {                                                \
    const unsigned cw = cw##S;                                            \
    half8 a0, a1;                                                         \
    { unsigned ud  = ((cw >> sh0) & 255u) - (unsigned)sb32;               \
      unsigned ud2 = ud - 4u;                                             \
      u64 lo = (ud  < 4u) ? (0x3C00ull << ((ud  & 3u) << 4)) : 0ull;      \
      u64 hi = (ud2 < 4u) ? (0x3C00ull << ((ud2 & 3u) << 4)) : 0ull;      \
      union { u64 q[2]; half8 h; } uu; uu.q[0] = lo; uu.q[1] = hi;        \
      a0 = uu.h; }                                                        \
    { unsigned ud  = ((cw >> (sh0 + 16)) & 255u) - (unsigned)sb32;        \
      unsigned ud2 = ud - 4u;                                             \
      u64 lo = (ud  < 4u) ? (0x3C00ull << ((ud  & 3u) << 4)) : 0ull;      \
      u64 hi = (ud2 < 4u) ? (0x3C00ull << ((ud2 & 3u) << 4)) : 0ull;      \
      union { u64 q[2]; half8 h; } uu; uu.q[0] = lo; uu.q[1] = hi;        \
      a1 = uu.h; }                                                        \
    union { uint4 u; half8 h; } q0, q1;                                   \
    q0.u = b##S##0; q1.u = b##S##1;                                       \
    acc00 = __builtin_amdgcn_mfma_f32_32x32x16_f16(a0, q0.h, acc00, 0, 0, 0); \
    acc01 = __builtin_amdgcn_mfma_f32_32x32x16_f16(a0, q1.h, acc01, 0, 0, 0); \
    acc10 = __builtin_amdgcn_mfma_f32_32x32x16_f16(a1, q0.h, acc10, 0, 0, 0); \
    acc11 = __builtin_amdgcn_mfma_f32_32x32x16_f16(a1, q1.h, acc11, 0, 0, 0); \
} while (0)

__global__ __launch_bounds__(256, 2) void decode_kernel(const unsigned* __restrict__ codesG,
                                                        const uint4* __restrict__ Bpk,
                                                        float* __restrict__ out) {
    const int tid = threadIdx.x;
    const int bn  = blockIdx.x >> 2;        // 0..127 (128-row group)
    const int bm  = blockIdx.x & 3;         // 0..3   (128-col strip)
    const int n0  = bn << 7;
    const int m0  = bm << 7;

    const int w    = tid >> 6;              // wave 0..3
    const int lane = tid & 63;
    const int wn   = w >> 1;                // 64-row half (= one code tile)
    const int wm   = w & 1;                 // 64-col half (= 2 mt32 tiles)
    const int sh0  = ((lane >> 4) & 1) << 3;  // byte shift: row bits 4
    const int sb32 = (lane >> 5) << 3;        // lane's k-slot base (0 or 8)

    // B frag (ks, mt) at Bp[(ks*16 + mt)*64]; code word at cG[ks]
    const uint4* Bp = Bpk + ((bm << 2) + (wm << 1)) * 64 + lane;
    const unsigned* cG = codesG + ((size_t)((bn << 1) | wn) << 10) + ((lane & 15) << 6);

    f32x16 acc00 = {0.f}, acc01 = {0.f}, acc10 = {0.f}, acc11 = {0.f};

    uint4 bA0, bA1; unsigned cwA;
    uint4 bB0, bB1; unsigned cwB;
    uint4 bC0, bC1; unsigned cwC;
    uint4 bD0, bD1; unsigned cwD;

    // prologue: 4 k-steps in flight (12 outstanding loads)
    LOADSET(A, 0)
    LOADSET(B, 1)
    LOADSET(C, 2)
    LOADSET(D, 3)

#pragma unroll 1
    for (int g = 0; g < 16; ++g) {
        const int ks = g << 2;
        const bool more = g < 15;
        COMPUTESET(A); if (more) { LOADSET(A, ks + 4) }
        COMPUTESET(B); if (more) { LOADSET(B, ks + 5) }
        COMPUTESET(C); if (more) { LOADSET(C, ks + 6) }
        COMPUTESET(D); if (more) { LOADSET(D, ks + 7) }
    }

    // ---- epilogue: 32x32 D layout col=lane&31, row=(r&3)+8*(r>>2)+4*(lane>>5) ----
    const int colr = lane & 31;
    const int rhi  = (lane >> 5) << 2;
    const int rb0  = n0 + (wn << 6);             // nt=0 row base
    const size_t mcol = m0 + (wm << 6) + colr;
#pragma unroll
    for (int r = 0; r < 16; ++r) {
        const int row = (r & 3) + ((r >> 2) << 3) + rhi;
        out[(size_t)(rb0 + row) * MM + mcol]            = acc00[r];
        out[(size_t)(rb0 + row) * MM + mcol + 32]       = acc01[r];
        out[(size_t)(rb0 + 32 + row) * MM + mcol]       = acc10[r];
        out[(size_t)(rb0 + 32 + row) * MM + mcol + 32]  = acc11[r];
    }
}

// ---------------------------------------------------------------------------
extern "C" void kernel_launch(void* const* d_in, const int* in_sizes, int n_in,
                              void* d_out, int out_size, void* d_ws, size_t ws_size,
                              hipStream_t stream) {
    const float* I = (const float*)d_in[0];  // (N, D) fp32
    const float* A = (const float*)d_in[1];  // (C, 8, 4) fp32
    const float* T = (const float*)d_in[2];  // (C*15,) fp32
    const float* L = (const float*)d_in[3];  // (M, C, K) fp32
    // d_in[4] = S, d_in[5] = B: structural constants, hard-coded.

    uint4* Bpk = (uint4*)d_ws;                               // 1 MB fp16 LUT frags (32x32 order)
    unsigned* codesG = (unsigned*)((char*)d_ws + (1 << 20)); // 1 MB packed codes
    float* out = (float*)d_out;                              // (N, M) fp32

    hipLaunchKernelGGL(prep_kernel, dim3(1280), dim3(256), 0, stream, I, A, T, L, Bpk, codesG);
    hipLaunchKernelGGL(decode_kernel, dim3(512), dim3(256), 0, stream, codesG, Bpk, out);
}